// Round 5
// baseline (1355.605 us; speedup 1.0000x reference)
//
#include <hip/hip_runtime.h>
#include <math.h>

constexpr int D  = 64;
constexpr int T  = 200;
constexpr int H0 = 80;
constexpr int H1 = 40;
constexpr int BLOCK = 256;
constexpr float NEG_INF_V = -4294967295.0f;

typedef float f8 __attribute__((ext_vector_type(8)));

// ---------------- Pre-kernel: fold per-batch layer-1 weights into d_ws ------
// FOLDED=1: weff[b][d][h] = W0[64+d][h] - W0[128+d][h] + q_d*W0[192+d][h]
// FOLDED=0: wbc[d][h]     = W0[64+d][h] - W0[128+d][h]   (b==0 only, 20 KB)
// Both:     biasq[b][h]   = b0[h] + sum_d q_d*(W0[d][h] + W0[128+d][h])
template<int FOLDED>
__global__ __launch_bounds__(256) void fold_k(
    const float* __restrict__ q, const float* __restrict__ W0,
    const float* __restrict__ b0, float* __restrict__ wout,
    float* __restrict__ biasq)
{
    const int b = blockIdx.x, tid = threadIdx.x;
    const float* qb = q + (size_t)b * D;
    if (FOLDED) {
        float* wb = wout + (size_t)b * (D * H0);
        for (int i = tid; i < D * H0; i += 256) {
            int d = i / H0;
            wb[i] = W0[64 * H0 + i] - W0[128 * H0 + i] + qb[d] * W0[192 * H0 + i];
        }
    } else if (b == 0) {
        for (int i = tid; i < D * H0; i += 256)
            wout[i] = W0[64 * H0 + i] - W0[128 * H0 + i];
    }
    if (tid < H0) {
        float acc = b0[tid];
        #pragma unroll 4
        for (int d = 0; d < D; ++d)
            acc = fmaf(qb[d], W0[d * H0 + tid] + W0[(128 + d) * H0 + tid], acc);
        biasq[(size_t)b * H0 + tid] = acc;
    }
}

// ---------------- Main kernel ----------------
// Weights/bias arrive via wave-uniform loads -> scalar path (s_load, SGPR
// operands folded into v_fma). Per-wave weight traffic is 33 KB instead of
// 2.1 MB (the per-lane LDS-broadcast design is LDS-BW-bound at ~330 us; R4).
// The d-loops are FULLY unrolled: kr[] indices must be compile-time constants
// or the allocator demotes kr and re-loads k from global every hbi (R3/R4).
template<int FOLDED>
__global__ __launch_bounds__(BLOCK, 4) void attn_main(
    const float* __restrict__ k, const float* __restrict__ v,
    const float* __restrict__ q,
    const float* __restrict__ wA,      // FOLDED ? weff[b] : wbc (shared)
    const float* __restrict__ wB,      // W0 + 192*H0 (q*k rows; !FOLDED only)
    const float* __restrict__ biasq,
    const float* __restrict__ a0, const float* __restrict__ W1,
    const float* __restrict__ b1, const float* __restrict__ a1,
    const float* __restrict__ Wo, const float* __restrict__ bo,
    const int* __restrict__ mask, float* __restrict__ out)
{
    __shared__ float s_w[BLOCK];
    __shared__ float s_red[8];
    __shared__ float s_part[4][D];

    const int tid = threadIdx.x;
    const int b   = blockIdx.x;

    const float* wAb = FOLDED ? wA + (size_t)b * (D * H0) : wA;
    const float* bq  = biasq + (size_t)b * H0;
    const float* qb  = q + (size_t)b * D;

    const int mval = (tid < T) ? mask[(size_t)b * T + tid] : 0;

    float logit;
    if (tid < T) {
        const float4* kp4 = (const float4*)(k + ((size_t)b * T + tid) * D);
        float4 kr[16];
        #pragma unroll
        for (int i = 0; i < 16; ++i) kr[i] = kp4[i];

        float h1acc[H1];
        #pragma unroll
        for (int g = 0; g < H1; ++g) h1acc[g] = 0.0f;

        #pragma unroll 1
        for (int hbi = 0; hbi < 10; ++hbi) {
            const int hb = hbi * 8;
            f8 bqv = *(const f8*)(bq + hb);      // uniform -> s_load
            float acc[8];
            #pragma unroll
            for (int j = 0; j < 8; ++j) acc[j] = bqv[j];

            #pragma unroll
            for (int d4 = 0; d4 < 16; ++d4) {    // FULL unroll: kr stays in VGPRs
                const float4 kd = kr[d4];
                float4 qv;
                if (!FOLDED) qv = *(const float4*)(qb + d4 * 4);  // uniform
                #pragma unroll
                for (int dd = 0; dd < 4; ++dd) {
                    const int d = d4 * 4 + dd;
                    const float kv = (dd == 0) ? kd.x : (dd == 1) ? kd.y
                                   : (dd == 2) ? kd.z : kd.w;
                    f8 wa = *(const f8*)(wAb + d * H0 + hb);      // uniform
                    #pragma unroll
                    for (int j = 0; j < 8; ++j) acc[j] = fmaf(kv, wa[j], acc[j]);
                    if (!FOLDED) {
                        const float qd = (dd == 0) ? qv.x : (dd == 1) ? qv.y
                                       : (dd == 2) ? qv.z : qv.w;
                        const float pd = kv * qd;
                        f8 wd = *(const f8*)(wB + d * H0 + hb);   // uniform
                        #pragma unroll
                        for (int j = 0; j < 8; ++j) acc[j] = fmaf(pd, wd[j], acc[j]);
                    }
                }
            }

            // PReLU + layer-2 accumulation (uniform weight loads)
            f8 al = *(const f8*)(a0 + hb);
            #pragma unroll
            for (int j = 0; j < 8; ++j) {
                const float x = acc[j];
                const float h0v = (x >= 0.0f) ? x : al[j] * x;
                const float* w1r = W1 + (hb + j) * H1;
                #pragma unroll
                for (int g8 = 0; g8 < 5; ++g8) {
                    f8 w = *(const f8*)(w1r + g8 * 8);
                    #pragma unroll
                    for (int u = 0; u < 8; ++u)
                        h1acc[g8 * 8 + u] = fmaf(h0v, w[u], h1acc[g8 * 8 + u]);
                }
            }
        }

        float lg = bo[0];
        #pragma unroll
        for (int g8 = 0; g8 < 5; ++g8) {
            f8 bb = *(const f8*)(b1 + g8 * 8);
            f8 aa = *(const f8*)(a1 + g8 * 8);
            f8 ww = *(const f8*)(Wo + g8 * 8);
            #pragma unroll
            for (int u = 0; u < 8; ++u) {
                const float x = h1acc[g8 * 8 + u] + bb[u];
                const float hv = (x >= 0.0f) ? x : aa[u] * x;
                lg = fmaf(hv, ww[u], lg);
            }
        }
        logit = (mval == 0) ? NEG_INF_V : lg;
    } else {
        logit = -INFINITY;   // pads: exp() = 0 even in all-masked rows
    }

    // ---- Softmax: wave shuffle reduce + tiny LDS combine ----
    float m = logit;
    #pragma unroll
    for (int off = 32; off > 0; off >>= 1) m = fmaxf(m, __shfl_xor(m, off));
    if ((tid & 63) == 0) s_red[tid >> 6] = m;
    __syncthreads();
    m = fmaxf(fmaxf(s_red[0], s_red[1]), fmaxf(s_red[2], s_red[3]));
    const float e = expf(logit - m);
    s_w[tid] = e;
    float ssum = e;
    #pragma unroll
    for (int off = 32; off > 0; off >>= 1) ssum += __shfl_xor(ssum, off);
    if ((tid & 63) == 0) s_red[4 + (tid >> 6)] = ssum;
    __syncthreads();
    const float inv = 1.0f / (s_red[4] + s_red[5] + s_red[6] + s_red[7]);

    // ---- out[b,d] = sum_t w_t * v[b,t,d] (coalesced in d) ----
    const int d = tid & (D - 1);
    const int c = tid >> 6;
    constexpr int TC = T / 4;          // 50
    float acc2 = 0.0f;
    const float* vp = v + ((size_t)b * T + c * TC) * D + d;
    #pragma unroll 4
    for (int t = 0; t < TC; ++t)
        acc2 = fmaf(s_w[c * TC + t], vp[t * D], acc2);
    s_part[c][d] = acc2;
    __syncthreads();
    if (tid < D) {
        out[(size_t)b * D + tid] =
            (s_part[0][tid] + s_part[1][tid] + s_part[2][tid] + s_part[3][tid]) * inv;
    }
}

extern "C" void kernel_launch(void* const* d_in, const int* in_sizes, int n_in,
                              void* d_out, int out_size, void* d_ws, size_t ws_size,
                              hipStream_t stream) {
    const float* q  = (const float*)d_in[0];
    const float* k  = (const float*)d_in[1];
    const float* v  = (const float*)d_in[2];
    const float* W0 = (const float*)d_in[3];
    const float* b0 = (const float*)d_in[4];
    const float* a0 = (const float*)d_in[5];
    const float* W1 = (const float*)d_in[6];
    const float* b1 = (const float*)d_in[7];
    const float* a1 = (const float*)d_in[8];
    const float* Wo = (const float*)d_in[9];
    const float* bo = (const float*)d_in[10];
    const int*  mask = (const int*)d_in[11];
    float* out = (float*)d_out;
    float* ws  = (float*)d_ws;

    const int B = in_sizes[0] / D;            // 2048
    const float* w0d = W0 + 192 * H0;         // q*k weight rows

    const size_t need_fold = ((size_t)B * D * H0 + (size_t)B * H0) * sizeof(float);
    if (ws_size >= need_fold) {
        float* weff  = ws;
        float* biasq = ws + (size_t)B * D * H0;
        fold_k<1><<<dim3(B), dim3(256), 0, stream>>>(q, W0, b0, weff, biasq);
        attn_main<1><<<dim3(B), dim3(BLOCK), 0, stream>>>(
            k, v, q, weff, w0d, biasq, a0, W1, b1, a1, Wo, bo, mask, out);
    } else {
        float* wbc   = ws;                    // [64][80]
        float* biasq = ws + D * H0;
        fold_k<0><<<dim3(B), dim3(256), 0, stream>>>(q, W0, b0, wbc, biasq);
        attn_main<0><<<dim3(B), dim3(BLOCK), 0, stream>>>(
            k, v, q, wbc, w0d, biasq, a0, W1, b1, a1, Wo, bo, mask, out);
    }
}

// Round 6
// 377.425 us; speedup vs baseline: 3.5917x; 3.5917x over previous
//
#include <hip/hip_runtime.h>
#include <math.h>

constexpr int D  = 64;
constexpr int T  = 200;
constexpr int H0 = 80;
constexpr int H1 = 40;
constexpr int BLOCK = 256;
constexpr float NEG_INF_V = -4294967295.0f;

typedef float f8 __attribute__((ext_vector_type(8)));

// ---------------- Pre-kernel: fold per-batch layer-1 weights into d_ws ------
// FOLDED=1: weff[b][d][h] = W0[64+d][h] - W0[128+d][h] + q_d*W0[192+d][h]
// FOLDED=0: wbc[d][h]     = W0[64+d][h] - W0[128+d][h]   (b==0 only)
// Both:     biasq[b][h]   = b0[h] + sum_d q_d*(W0[d][h] + W0[128+d][h])
//           W1T[g][j]     = W1[j][g]   (b==0; lets layer-2 loop g at runtime
//                                       with constant-indexed acc[j])
template<int FOLDED>
__global__ __launch_bounds__(256) void fold_k(
    const float* __restrict__ q, const float* __restrict__ W0,
    const float* __restrict__ b0, const float* __restrict__ W1,
    float* __restrict__ wout, float* __restrict__ biasq,
    float* __restrict__ W1T)
{
    const int b = blockIdx.x, tid = threadIdx.x;
    const float* qb = q + (size_t)b * D;
    if (FOLDED) {
        float* wb = wout + (size_t)b * (D * H0);
        for (int i = tid; i < D * H0; i += 256) {
            int d = i / H0;
            wb[i] = W0[64 * H0 + i] - W0[128 * H0 + i] + qb[d] * W0[192 * H0 + i];
        }
    } else if (b == 0) {
        for (int i = tid; i < D * H0; i += 256)
            wout[i] = W0[64 * H0 + i] - W0[128 * H0 + i];
    }
    if (b == 0) {
        for (int i = tid; i < H0 * H1; i += 256) {
            int j = i / H1, g = i - j * H1;
            W1T[g * H0 + j] = W1[i];
        }
    }
    if (tid < H0) {
        float acc = b0[tid];
        #pragma unroll 4
        for (int d = 0; d < D; ++d)
            acc = fmaf(qb[d], W0[d * H0 + tid] + W0[(128 + d) * H0 + tid], acc);
        biasq[(size_t)b * H0 + tid] = acc;
    }
}

// ---------------- Main kernel ----------------
// Loop-interchanged MLP: the H0=80 accumulators live in registers (computed
// values -> the allocator cannot demote them); k streams through, each element
// consumed immediately (no long-lived loaded array -> no R2..R5 k-refetch).
// All weights arrive via wave-uniform f8 loads (scalar s_load path).
// Layer 2 uses W1T so the g-loop is runtime while acc[] indices stay constant.
template<int FOLDED>
__global__ __launch_bounds__(BLOCK, 4) void attn_main(
    const float* __restrict__ k, const float* __restrict__ v,
    const float* __restrict__ q,
    const float* __restrict__ wA,      // FOLDED ? weff[b] : wbc (shared)
    const float* __restrict__ wB,      // W0 + 192*H0 (q*k rows; !FOLDED only)
    const float* __restrict__ biasq, const float* __restrict__ W1T,
    const float* __restrict__ a0,
    const float* __restrict__ b1, const float* __restrict__ a1,
    const float* __restrict__ Wo, const float* __restrict__ bo,
    const int* __restrict__ mask, float* __restrict__ out)
{
    __shared__ float s_w[BLOCK];
    __shared__ float s_red[8];
    __shared__ float s_part[4][D];

    const int tid = threadIdx.x;
    const int b   = blockIdx.x;

    const float* wAb = FOLDED ? wA + (size_t)b * (D * H0) : wA;
    const float* bq  = biasq + (size_t)b * H0;
    const float* qb  = q + (size_t)b * D;

    const int mval = (tid < T) ? mask[(size_t)b * T + tid] : 0;

    float logit;
    if (tid < T) {
        float acc[H0];
        #pragma unroll
        for (int h8 = 0; h8 < 10; ++h8) {
            f8 bv = *(const f8*)(bq + h8 * 8);           // uniform
            #pragma unroll
            for (int j = 0; j < 8; ++j) acc[h8 * 8 + j] = bv[j];
        }

        // ---- Layer 1: stream k once; 320 FMA per float4 of k ----
        const float4* kp4 = (const float4*)(k + ((size_t)b * T + tid) * D);
        #pragma unroll 1
        for (int d4 = 0; d4 < 16; ++d4) {
            const float4 kd = kp4[d4];                    // used immediately
            const float* wr = wAb + (size_t)(d4 * 4) * H0;
            float4 qv;
            if (!FOLDED) qv = *(const float4*)(qb + d4 * 4);  // uniform
            #pragma unroll
            for (int dd = 0; dd < 4; ++dd) {
                const float kv = (dd == 0) ? kd.x : (dd == 1) ? kd.y
                               : (dd == 2) ? kd.z : kd.w;
                #pragma unroll
                for (int h8 = 0; h8 < 10; ++h8) {
                    f8 w = *(const f8*)(wr + dd * H0 + h8 * 8);   // uniform
                    #pragma unroll
                    for (int j = 0; j < 8; ++j)
                        acc[h8 * 8 + j] = fmaf(kv, w[j], acc[h8 * 8 + j]);
                }
                if (!FOLDED) {
                    const float qd = (dd == 0) ? qv.x : (dd == 1) ? qv.y
                                   : (dd == 2) ? qv.z : qv.w;
                    const float pd = kv * qd;
                    const float* wdr = wB + (size_t)(d4 * 4 + dd) * H0;
                    #pragma unroll
                    for (int h8 = 0; h8 < 10; ++h8) {
                        f8 w = *(const f8*)(wdr + h8 * 8);        // uniform
                        #pragma unroll
                        for (int j = 0; j < 8; ++j)
                            acc[h8 * 8 + j] = fmaf(pd, w[j], acc[h8 * 8 + j]);
                    }
                }
            }
        }

        // ---- PReLU layer 1 in place (constant indices) ----
        #pragma unroll
        for (int h8 = 0; h8 < 10; ++h8) {
            f8 al = *(const f8*)(a0 + h8 * 8);            // uniform
            #pragma unroll
            for (int j = 0; j < 8; ++j) {
                const float x = acc[h8 * 8 + j];
                acc[h8 * 8 + j] = (x >= 0.0f) ? x : al[j] * x;
            }
        }

        // ---- Layer 2 + output head fused: runtime g loop, constant acc[] ----
        float lg = bo[0];
        #pragma unroll 1
        for (int g = 0; g < H1; ++g) {
            const float* wg = W1T + g * H0;
            float sum = b1[g];                            // uniform
            #pragma unroll
            for (int h8 = 0; h8 < 10; ++h8) {
                f8 w = *(const f8*)(wg + h8 * 8);         // uniform
                #pragma unroll
                for (int j = 0; j < 8; ++j)
                    sum = fmaf(acc[h8 * 8 + j], w[j], sum);
            }
            const float hv = (sum >= 0.0f) ? sum : a1[g] * sum;
            lg = fmaf(hv, Wo[g], lg);
        }
        logit = (mval == 0) ? NEG_INF_V : lg;
    } else {
        logit = -INFINITY;   // pads: exp() = 0 even in all-masked rows
    }

    // ---- Softmax: wave shuffle reduce + tiny LDS combine ----
    float m = logit;
    #pragma unroll
    for (int off = 32; off > 0; off >>= 1) m = fmaxf(m, __shfl_xor(m, off));
    if ((tid & 63) == 0) s_red[tid >> 6] = m;
    __syncthreads();
    m = fmaxf(fmaxf(s_red[0], s_red[1]), fmaxf(s_red[2], s_red[3]));
    const float e = expf(logit - m);
    s_w[tid] = e;
    float ssum = e;
    #pragma unroll
    for (int off = 32; off > 0; off >>= 1) ssum += __shfl_xor(ssum, off);
    if ((tid & 63) == 0) s_red[4 + (tid >> 6)] = ssum;
    __syncthreads();
    const float inv = 1.0f / (s_red[4] + s_red[5] + s_red[6] + s_red[7]);

    // ---- out[b,d] = sum_t w_t * v[b,t,d] (coalesced in d) ----
    const int d = tid & (D - 1);
    const int c = tid >> 6;
    constexpr int TC = T / 4;          // 50
    float acc2 = 0.0f;
    const float* vp = v + ((size_t)b * T + c * TC) * D + d;
    #pragma unroll 4
    for (int t = 0; t < TC; ++t)
        acc2 = fmaf(s_w[c * TC + t], vp[t * D], acc2);
    s_part[c][d] = acc2;
    __syncthreads();
    if (tid < D) {
        out[(size_t)b * D + tid] =
            (s_part[0][tid] + s_part[1][tid] + s_part[2][tid] + s_part[3][tid]) * inv;
    }
}

extern "C" void kernel_launch(void* const* d_in, const int* in_sizes, int n_in,
                              void* d_out, int out_size, void* d_ws, size_t ws_size,
                              hipStream_t stream) {
    const float* q  = (const float*)d_in[0];
    const float* k  = (const float*)d_in[1];
    const float* v  = (const float*)d_in[2];
    const float* W0 = (const float*)d_in[3];
    const float* b0 = (const float*)d_in[4];
    const float* a0 = (const float*)d_in[5];
    const float* W1 = (const float*)d_in[6];
    const float* b1 = (const float*)d_in[7];
    const float* a1 = (const float*)d_in[8];
    const float* Wo = (const float*)d_in[9];
    const float* bo = (const float*)d_in[10];
    const int*  mask = (const int*)d_in[11];
    float* out = (float*)d_out;
    float* ws  = (float*)d_ws;

    const int B = in_sizes[0] / D;            // 2048
    const float* w0d = W0 + 192 * H0;         // q*k weight rows

    const size_t n_weff  = (size_t)B * D * H0;
    const size_t n_biasq = (size_t)B * H0;
    const size_t n_w1t   = (size_t)H0 * H1;
    const size_t need_fold  = (n_weff + n_biasq + n_w1t) * sizeof(float);
    if (ws_size >= need_fold) {
        float* weff  = ws;
        float* biasq = weff + n_weff;
        float* W1T   = biasq + n_biasq;
        fold_k<1><<<dim3(B), dim3(256), 0, stream>>>(q, W0, b0, W1, weff, biasq, W1T);
        attn_main<1><<<dim3(B), dim3(BLOCK), 0, stream>>>(
            k, v, q, weff, w0d, biasq, W1T, a0, b1, a1, Wo, bo, mask, out);
    } else {
        float* wbc   = ws;                    // [64][80]
        float* biasq = wbc + (size_t)D * H0;
        float* W1T   = biasq + n_biasq;
        fold_k<0><<<dim3(B), dim3(256), 0, stream>>>(q, W0, b0, W1, wbc, biasq, W1T);
        attn_main<0><<<dim3(B), dim3(BLOCK), 0, stream>>>(
            k, v, q, wbc, w0d, biasq, W1T, a0, b1, a1, Wo, bo, mask, out);
    }
}

// Round 7
// 324.430 us; speedup vs baseline: 4.1784x; 1.1633x over previous
//
#include <hip/hip_runtime.h>
#include <math.h>

constexpr int D  = 64;
constexpr int T  = 200;
constexpr int H0 = 80;
constexpr int H1 = 40;
constexpr int BLOCK = 256;
constexpr float NEG_INF_V = -4294967295.0f;

typedef float f8 __attribute__((ext_vector_type(8)));
typedef short short8 __attribute__((ext_vector_type(8)));
typedef float f32x4 __attribute__((ext_vector_type(4)));

// Split fp32 into two bf16 (RNE): x ~= hi + lo, |x-hi-lo| <= 2^-18|x|.
__device__ inline void split_bf16(float x, unsigned short& hi, unsigned short& lo) {
    union { float f; unsigned u; } a; a.f = x;
    unsigned r = a.u + 0x7FFF + ((a.u >> 16) & 1);
    hi = (unsigned short)(r >> 16);
    union { unsigned u; float f; } h; h.u = (unsigned)hi << 16;
    union { float f; unsigned u; } bvu; bvu.f = x - h.f;
    unsigned r2 = bvu.u + 0x7FFF + ((bvu.u >> 16) & 1);
    lo = (unsigned short)(r2 >> 16);
}

// ============ Fold kernel: pack split-bf16 MFMA B-fragments into ws =========
// weff[b][kk][n] = W0[64+kk][n] - W0[128+kk][n] + q_kk*W0[192+kk][n]
// B-fragment layout (16x16x32): lane holds B[k=ks*32+quad*8+j][n=nt*16+(lane&15)]
// wf{Hi,Lo}[((b*2+ks)*5+nt)*512 + lane*8 + j]
// W1 frags (b==0): k2 padded 80->96 (zeros), n padded 40->48 (zeros)
// biasq[b][h] = b0[h] + sum_d q_d*(W0[d][h] + W0[128+d][h])
__global__ __launch_bounds__(256) void fold_frag(
    const float* __restrict__ q, const float* __restrict__ W0,
    const float* __restrict__ b0, const float* __restrict__ W1,
    short* __restrict__ wfHi, short* __restrict__ wfLo,
    float* __restrict__ biasq, short* __restrict__ w1fHi,
    short* __restrict__ w1fLo)
{
    const int b = blockIdx.x, tid = threadIdx.x;
    const float* qb = q + (size_t)b * D;

    // weff fragments: 640 (ks,nt,lane) groups x 8 j
    for (int g = tid; g < 640; g += 256) {
        const int ks   = g / 320;
        const int r    = g - ks * 320;
        const int nt   = r >> 6;
        const int lane = r & 63;
        const int l16  = lane & 15, quad = lane >> 4;
        const int n    = nt * 16 + l16;
        short8 hi8, lo8;
        #pragma unroll
        for (int j = 0; j < 8; ++j) {
            const int kk = ks * 32 + quad * 8 + j;
            const float w = W0[(64 + kk) * H0 + n] - W0[(128 + kk) * H0 + n]
                          + qb[kk] * W0[(192 + kk) * H0 + n];
            unsigned short h, l; split_bf16(w, h, l);
            hi8[j] = (short)h; lo8[j] = (short)l;
        }
        const size_t o = ((size_t)(b * 2 + ks) * 5 + nt) * 512 + lane * 8;
        *(short8*)(wfHi + o) = hi8;
        *(short8*)(wfLo + o) = lo8;
    }
    // biasq
    if (tid < H0) {
        float acc = b0[tid];
        #pragma unroll 4
        for (int d = 0; d < D; ++d)
            acc = fmaf(qb[d], W0[d * H0 + tid] + W0[(128 + d) * H0 + tid], acc);
        biasq[(size_t)b * H0 + tid] = acc;
    }
    // W1 fragments (shared): 576 (k2s,nt2,lane) groups x 8 j
    if (b == 0) {
        for (int g = tid; g < 576; g += 256) {
            const int k2s  = g / 192;
            const int r    = g - k2s * 192;
            const int nt2  = r >> 6;
            const int lane = r & 63;
            const int l16  = lane & 15, quad = lane >> 4;
            const int n    = nt2 * 16 + l16;
            short8 hi8, lo8;
            #pragma unroll
            for (int j = 0; j < 8; ++j) {
                const int k2 = k2s * 32 + quad * 8 + j;
                const float w = (k2 < H0 && n < H1) ? W1[k2 * H1 + n] : 0.0f;
                unsigned short h, l; split_bf16(w, h, l);
                hi8[j] = (short)h; lo8[j] = (short)l;
            }
            const size_t o = (size_t)(k2s * 3 + nt2) * 512 + lane * 8;
            *(short8*)(w1fHi + o) = hi8;
            *(short8*)(w1fLo + o) = lo8;
        }
    }
}

// ============ Main kernel: MFMA MLP + softmax + w.v ============
// One block per batch, 4 waves. Wave w owns M-tiles {w, w+4, ...} of 13
// (M=200 pad 208). Layer1: C1 = K[16x64] x Weff[64x80] via 6 split-MFMAs per
// N-tile. PReLU in C-layout, h0 -> per-wave LDS tile [16][96] (split bf16).
// Layer2 from LDS A-frags x W1 frags. Head reduced via shfl_xor. No barriers
// inside the wave loop (same-wave LDS, lgkmcnt(0) only).
__global__ __launch_bounds__(BLOCK, 4) void attn_mfma(
    const float* __restrict__ k, const float* __restrict__ v,
    const short* __restrict__ wfHi, const short* __restrict__ wfLo,
    const float* __restrict__ biasq,
    const short* __restrict__ w1fHi, const short* __restrict__ w1fLo,
    const float* __restrict__ a0, const float* __restrict__ b1,
    const float* __restrict__ a1, const float* __restrict__ Wo,
    const float* __restrict__ bo, const int* __restrict__ mask,
    float* __restrict__ out)
{
    __shared__ unsigned short s_h0hi[4][16 * 96];   // 12 KB
    __shared__ unsigned short s_h0lo[4][16 * 96];   // 12 KB
    __shared__ float s_logits[208];
    __shared__ float s_biasq[H0];
    __shared__ float s_a0[H0];
    __shared__ float s_b1p[48], s_a1p[48], s_Wop[48];
    __shared__ float s_w[BLOCK];
    __shared__ float s_red[8];
    __shared__ float s_part[4][D];

    const int tid  = threadIdx.x;
    const int b    = blockIdx.x;
    const int wv   = tid >> 6;
    const int lane = tid & 63;
    const int l16  = lane & 15;
    const int quad = lane >> 4;

    if (tid < H0) { s_biasq[tid] = biasq[(size_t)b * H0 + tid]; s_a0[tid] = a0[tid]; }
    if (tid < 48) {
        s_b1p[tid] = (tid < H1) ? b1[tid] : 0.0f;
        s_a1p[tid] = (tid < H1) ? a1[tid] : 0.0f;
        s_Wop[tid] = (tid < H1) ? Wo[tid] : 0.0f;
    }
    __syncthreads();

    for (int mt = wv; mt < 13; mt += 4) {
        // zero k2-pad cols [80,96) of this wave's tile (8 B per lane per array)
        {
            const int r = lane >> 2, c = 80 + (lane & 3) * 4;
            *(unsigned long long*)&s_h0hi[wv][r * 96 + c] = 0ULL;
            *(unsigned long long*)&s_h0lo[wv][r * 96 + c] = 0ULL;
        }
        // ---- A1 fragments: k row (clamped for pad rows), split bf16 ----
        int row = mt * 16 + l16; if (row > T - 1) row = T - 1;
        const float* krow = k + ((size_t)b * T + row) * D + quad * 8;
        short8 a1hi[2], a1lo[2];
        #pragma unroll
        for (int ks = 0; ks < 2; ++ks) {
            float4 x0 = *(const float4*)(krow + ks * 32);
            float4 x1 = *(const float4*)(krow + ks * 32 + 4);
            float xs[8] = {x0.x, x0.y, x0.z, x0.w, x1.x, x1.y, x1.z, x1.w};
            #pragma unroll
            for (int j = 0; j < 8; ++j) {
                unsigned short h, l; split_bf16(xs[j], h, l);
                a1hi[ks][j] = (short)h; a1lo[ks][j] = (short)l;
            }
        }
        // ---- Layer 1: 5 N-tiles ----
        #pragma unroll 1
        for (int nt = 0; nt < 5; ++nt) {
            f32x4 acc = {0.0f, 0.0f, 0.0f, 0.0f};
            #pragma unroll
            for (int ks = 0; ks < 2; ++ks) {
                const size_t o = ((size_t)(b * 2 + ks) * 5 + nt) * 512 + lane * 8;
                short8 bh = *(const short8*)(wfHi + o);
                short8 bl = *(const short8*)(wfLo + o);
                acc = __builtin_amdgcn_mfma_f32_16x16x32_bf16(a1hi[ks], bh, acc, 0, 0, 0);
                acc = __builtin_amdgcn_mfma_f32_16x16x32_bf16(a1hi[ks], bl, acc, 0, 0, 0);
                acc = __builtin_amdgcn_mfma_f32_16x16x32_bf16(a1lo[ks], bh, acc, 0, 0, 0);
            }
            // PReLU + split-store to LDS tile (C-layout: row=quad*4+reg, col=h)
            const int h = nt * 16 + l16;
            const float bq = s_biasq[h], al = s_a0[h];
            #pragma unroll
            for (int reg = 0; reg < 4; ++reg) {
                const float x  = acc[reg] + bq;
                const float h0 = (x >= 0.0f) ? x : al * x;
                unsigned short hh, hl; split_bf16(h0, hh, hl);
                const int addr = (quad * 4 + reg) * 96 + h;
                s_h0hi[wv][addr] = hh;
                s_h0lo[wv][addr] = hl;
            }
        }
        __asm__ __volatile__("s_waitcnt lgkmcnt(0)" ::: "memory");

        // ---- Layer 2 A-fragments from LDS (A-layout: m=l16 row, k2=quad*8+j) ----
        short8 a2hi[3], a2lo[3];
        #pragma unroll
        for (int k2s = 0; k2s < 3; ++k2s) {
            const int addr = l16 * 96 + k2s * 32 + quad * 8;
            a2hi[k2s] = *(const short8*)&s_h0hi[wv][addr];
            a2lo[k2s] = *(const short8*)&s_h0lo[wv][addr];
        }
        float part[4] = {0.0f, 0.0f, 0.0f, 0.0f};
        #pragma unroll 1
        for (int nt2 = 0; nt2 < 3; ++nt2) {
            f32x4 acc = {0.0f, 0.0f, 0.0f, 0.0f};
            #pragma unroll
            for (int k2s = 0; k2s < 3; ++k2s) {
                const size_t o = (size_t)(k2s * 3 + nt2) * 512 + lane * 8;
                short8 bh = *(const short8*)(w1fHi + o);
                short8 bl = *(const short8*)(w1fLo + o);
                acc = __builtin_amdgcn_mfma_f32_16x16x32_bf16(a2hi[k2s], bh, acc, 0, 0, 0);
                acc = __builtin_amdgcn_mfma_f32_16x16x32_bf16(a2hi[k2s], bl, acc, 0, 0, 0);
                acc = __builtin_amdgcn_mfma_f32_16x16x32_bf16(a2lo[k2s], bh, acc, 0, 0, 0);
            }
            const int g = nt2 * 16 + l16;
            const float bg = s_b1p[g], ag = s_a1p[g], wg = s_Wop[g];
            #pragma unroll
            for (int reg = 0; reg < 4; ++reg) {
                const float x  = acc[reg] + bg;
                const float hv = (x >= 0.0f) ? x : ag * x;
                part[reg] = fmaf(hv, wg, part[reg]);
            }
        }
        // reduce over the 16 cols (lane bits 0..3)
        #pragma unroll
        for (int off = 1; off < 16; off <<= 1) {
            #pragma unroll
            for (int reg = 0; reg < 4; ++reg)
                part[reg] += __shfl_xor(part[reg], off);
        }
        if (l16 == 0) {
            float4 p = {part[0], part[1], part[2], part[3]};
            *(float4*)&s_logits[mt * 16 + quad * 4] = p;
        }
    }
    __asm__ __volatile__("s_waitcnt lgkmcnt(0)" ::: "memory");
    __syncthreads();

    // ---- mask + softmax over T (pads -> -inf => exp 0) ----
    float logit = -INFINITY;
    if (tid < T)
        logit = (mask[(size_t)b * T + tid] == 0) ? NEG_INF_V : s_logits[tid];

    float m = logit;
    #pragma unroll
    for (int off = 32; off > 0; off >>= 1) m = fmaxf(m, __shfl_xor(m, off));
    if (lane == 0) s_red[wv] = m;
    __syncthreads();
    m = fmaxf(fmaxf(s_red[0], s_red[1]), fmaxf(s_red[2], s_red[3]));
    const float e = expf(logit - m);
    s_w[tid] = e;
    float ssum = e;
    #pragma unroll
    for (int off = 32; off > 0; off >>= 1) ssum += __shfl_xor(ssum, off);
    if (lane == 0) s_red[4 + wv] = ssum;
    __syncthreads();
    const float inv = 1.0f / (s_red[4] + s_red[5] + s_red[6] + s_red[7]);

    // ---- out[b,d] = sum_t w_t * v[b,t,d] (coalesced in d) ----
    const int d = tid & (D - 1);
    const int c = tid >> 6;
    constexpr int TC = T / 4;          // 50
    float acc2 = 0.0f;
    const float* vp = v + ((size_t)b * T + c * TC) * D + d;
    #pragma unroll 4
    for (int t = 0; t < TC; ++t)
        acc2 = fmaf(s_w[c * TC + t], vp[t * D], acc2);
    s_part[c][d] = acc2;
    __syncthreads();
    if (tid < D) {
        out[(size_t)b * D + tid] =
            (s_part[0][tid] + s_part[1][tid] + s_part[2][tid] + s_part[3][tid]) * inv;
    }
}

// ============ Fallback (small ws): R6's proven non-folded VALU path =========
__global__ __launch_bounds__(256) void fold_small(
    const float* __restrict__ q, const float* __restrict__ W0,
    const float* __restrict__ b0, const float* __restrict__ W1,
    float* __restrict__ wbc, float* __restrict__ biasq, float* __restrict__ W1T)
{
    const int b = blockIdx.x, tid = threadIdx.x;
    const float* qb = q + (size_t)b * D;
    if (b == 0) {
        for (int i = tid; i < D * H0; i += 256)
            wbc[i] = W0[64 * H0 + i] - W0[128 * H0 + i];
        for (int i = tid; i < H0 * H1; i += 256) {
            int j = i / H1, g = i - j * H1;
            W1T[g * H0 + j] = W1[i];
        }
    }
    if (tid < H0) {
        float acc = b0[tid];
        #pragma unroll 4
        for (int d = 0; d < D; ++d)
            acc = fmaf(qb[d], W0[d * H0 + tid] + W0[(128 + d) * H0 + tid], acc);
        biasq[(size_t)b * H0 + tid] = acc;
    }
}

__global__ __launch_bounds__(BLOCK, 4) void attn_valu(
    const float* __restrict__ k, const float* __restrict__ v,
    const float* __restrict__ q, const float* __restrict__ wbc,
    const float* __restrict__ wB, const float* __restrict__ biasq,
    const float* __restrict__ W1T, const float* __restrict__ a0,
    const float* __restrict__ b1, const float* __restrict__ a1,
    const float* __restrict__ Wo, const float* __restrict__ bo,
    const int* __restrict__ mask, float* __restrict__ out)
{
    __shared__ float s_w[BLOCK];
    __shared__ float s_red[8];
    __shared__ float s_part[4][D];
    const int tid = threadIdx.x, b = blockIdx.x;
    const float* bq = biasq + (size_t)b * H0;
    const float* qb = q + (size_t)b * D;
    const int mval = (tid < T) ? mask[(size_t)b * T + tid] : 0;
    float logit;
    if (tid < T) {
        float acc[H0];
        #pragma unroll
        for (int h8 = 0; h8 < 10; ++h8) {
            f8 bv = *(const f8*)(bq + h8 * 8);
            #pragma unroll
            for (int j = 0; j < 8; ++j) acc[h8 * 8 + j] = bv[j];
        }
        const float4* kp4 = (const float4*)(k + ((size_t)b * T + tid) * D);
        #pragma unroll 1
        for (int d4 = 0; d4 < 16; ++d4) {
            const float4 kd = kp4[d4];
            const float* wr = wbc + (size_t)(d4 * 4) * H0;
            float4 qv = *(const float4*)(qb + d4 * 4);
            #pragma unroll
            for (int dd = 0; dd < 4; ++dd) {
                const float kv = (dd == 0) ? kd.x : (dd == 1) ? kd.y
                               : (dd == 2) ? kd.z : kd.w;
                const float qd = (dd == 0) ? qv.x : (dd == 1) ? qv.y
                               : (dd == 2) ? qv.z : qv.w;
                const float pd = kv * qd;
                const float* wdr = wB + (size_t)(d4 * 4 + dd) * H0;
                #pragma unroll
                for (int h8 = 0; h8 < 10; ++h8) {
                    f8 w = *(const f8*)(wr + dd * H0 + h8 * 8);
                    f8 w2 = *(const f8*)(wdr + h8 * 8);
                    #pragma unroll
                    for (int j = 0; j < 8; ++j) {
                        acc[h8 * 8 + j] = fmaf(kv, w[j], acc[h8 * 8 + j]);
                        acc[h8 * 8 + j] = fmaf(pd, w2[j], acc[h8 * 8 + j]);
                    }
                }
            }
        }
        #pragma unroll
        for (int h8 = 0; h8 < 10; ++h8) {
            f8 al = *(const f8*)(a0 + h8 * 8);
            #pragma unroll
            for (int j = 0; j < 8; ++j) {
                const float x = acc[h8 * 8 + j];
                acc[h8 * 8 + j] = (x >= 0.0f) ? x : al[j] * x;
            }
        }
        float lg = bo[0];
        #pragma unroll 1
        for (int g = 0; g < H1; ++g) {
            const float* wg = W1T + g * H0;
            float sum = b1[g];
            #pragma unroll
            for (int h8 = 0; h8 < 10; ++h8) {
                f8 w = *(const f8*)(wg + h8 * 8);
                #pragma unroll
                for (int j = 0; j < 8; ++j) sum = fmaf(acc[h8 * 8 + j], w[j], sum);
            }
            const float hv = (sum >= 0.0f) ? sum : a1[g] * sum;
            lg = fmaf(hv, Wo[g], lg);
        }
        logit = (mval == 0) ? NEG_INF_V : lg;
    } else logit = -INFINITY;
    float m = logit;
    #pragma unroll
    for (int off = 32; off > 0; off >>= 1) m = fmaxf(m, __shfl_xor(m, off));
    if ((tid & 63) == 0) s_red[tid >> 6] = m;
    __syncthreads();
    m = fmaxf(fmaxf(s_red[0], s_red[1]), fmaxf(s_red[2], s_red[3]));
    const float e = expf(logit - m);
    s_w[tid] = e;
    float ssum = e;
    #pragma unroll
    for (int off = 32; off > 0; off >>= 1) ssum += __shfl_xor(ssum, off);
    if ((tid & 63) == 0) s_red[4 + (tid >> 6)] = ssum;
    __syncthreads();
    const float inv = 1.0f / (s_red[4] + s_red[5] + s_red[6] + s_red[7]);
    const int d = tid & (D - 1);
    const int c = tid >> 6;
    constexpr int TC = T / 4;
    float acc2 = 0.0f;
    const float* vp = v + ((size_t)b * T + c * TC) * D + d;
    #pragma unroll 4
    for (int t = 0; t < TC; ++t) acc2 = fmaf(s_w[c * TC + t], vp[t * D], acc2);
    s_part[c][d] = acc2;
    __syncthreads();
    if (tid < D)
        out[(size_t)b * D + tid] =
            (s_part[0][tid] + s_part[1][tid] + s_part[2][tid] + s_part[3][tid]) * inv;
}

extern "C" void kernel_launch(void* const* d_in, const int* in_sizes, int n_in,
                              void* d_out, int out_size, void* d_ws, size_t ws_size,
                              hipStream_t stream) {
    const float* q  = (const float*)d_in[0];
    const float* k  = (const float*)d_in[1];
    const float* v  = (const float*)d_in[2];
    const float* W0 = (const float*)d_in[3];
    const float* b0 = (const float*)d_in[4];
    const float* a0 = (const float*)d_in[5];
    const float* W1 = (const float*)d_in[6];
    const float* b1 = (const float*)d_in[7];
    const float* a1 = (const float*)d_in[8];
    const float* Wo = (const float*)d_in[9];
    const float* bo = (const float*)d_in[10];
    const int*  mask = (const int*)d_in[11];
    float* out = (float*)d_out;

    const int B = in_sizes[0] / D;            // 2048

    const size_t n_wf   = (size_t)B * 5120;   // ushorts per hi/lo array
    const size_t need = n_wf * 2 * 2 + (size_t)B * H0 * 4 + 4608 * 2 * 2;
    if (ws_size >= need) {
        short* wfHi  = (short*)d_ws;
        short* wfLo  = wfHi + n_wf;
        float* biasq = (float*)(wfLo + n_wf);
        short* w1fHi = (short*)(biasq + (size_t)B * H0);
        short* w1fLo = w1fHi + 4608;
        fold_frag<<<dim3(B), dim3(256), 0, stream>>>(
            q, W0, b0, W1, wfHi, wfLo, biasq, w1fHi, w1fLo);
        attn_mfma<<<dim3(B), dim3(BLOCK), 0, stream>>>(
            k, v, wfHi, wfLo, biasq, w1fHi, w1fLo,
            a0, b1, a1, Wo, bo, mask, out);
    } else {
        float* wbc   = (float*)d_ws;          // [64][80]
        float* biasq = wbc + (size_t)D * H0;
        float* W1T   = biasq + (size_t)B * H0;
        const float* w0d = W0 + 192 * H0;
        fold_small<<<dim3(B), dim3(256), 0, stream>>>(q, W0, b0, W1, wbc, biasq, W1T);
        attn_valu<<<dim3(B), dim3(BLOCK), 0, stream>>>(
            k, v, q, wbc, w0d, biasq, W1T, a0, b1, a1, Wo, bo, mask, out);
    }
}